// Round 2
// baseline (9227.011 us; speedup 1.0000x reference)
//
#include <hip/hip_runtime.h>
#include <hip/hip_bf16.h>
#include <math.h>

#define NN 16384
#define IN_DIM 256
#define HID 128
#define MAXL 128
#define NCLS 64
#define EPS 1e-5f

typedef unsigned short u16;
typedef unsigned int u32;

__device__ __forceinline__ float bf2f(u16 u) {
  union { u32 i; float f; } v; v.i = ((u32)u) << 16; return v.f;
}
__device__ __forceinline__ u16 f2bf(float f) {
  union { float f; u32 i; } v; v.f = f;
  u32 x = v.i;
  u32 r = (x + 0x7fffu + ((x >> 16) & 1u)) >> 16;
  return (u16)r;
}
__device__ __forceinline__ u32 pack2(float a, float b) {
  return (u32)f2bf(a) | ((u32)f2bf(b) << 16);
}
__device__ __forceinline__ float gelu_exact(float x) {
  return 0.5f * x * (1.0f + erff(x * 0.70710678118654752440f));
}
__device__ __forceinline__ void unp8(uint4 v, float* f) {
  union { u32 i; float f; } c;
  c.i = v.x << 16;          f[0] = c.f;
  c.i = v.x & 0xffff0000u;  f[1] = c.f;
  c.i = v.y << 16;          f[2] = c.f;
  c.i = v.y & 0xffff0000u;  f[3] = c.f;
  c.i = v.z << 16;          f[4] = c.f;
  c.i = v.z & 0xffff0000u;  f[5] = c.f;
  c.i = v.w << 16;          f[6] = c.f;
  c.i = v.w & 0xffff0000u;  f[7] = c.f;
}

// ---------------- K1: H = LN(GELU(node_feat @ local_W + b)) ----------------
// fp32 inputs; H stored bf16 in workspace (feeds the bf16 LDS tile in k_main).
__global__ __launch_bounds__(128) void k_local_encoder(
    const float* __restrict__ node_feat, const float* __restrict__ local_W,
    const float* __restrict__ local_b, const float* __restrict__ lnw,
    const float* __restrict__ lnb, u16* __restrict__ H) {
  __shared__ float x[IN_DIM];
  __shared__ float red[2][2];
  int n = blockIdx.x, j = threadIdx.x;
  const float* nf = node_feat + n * IN_DIM;
  x[j] = nf[j];
  x[j + 128] = nf[j + 128];
  __syncthreads();
  float acc = local_b[j];
#pragma unroll 8
  for (int k = 0; k < IN_DIM; ++k) acc += x[k] * local_W[k * HID + j];
  float g = gelu_exact(acc);
  float s = g, ss = g * g;
#pragma unroll
  for (int o = 32; o > 0; o >>= 1) {
    s += __shfl_down(s, o, 64);
    ss += __shfl_down(ss, o, 64);
  }
  int wave = j >> 6;
  if ((j & 63) == 0) { red[wave][0] = s; red[wave][1] = ss; }
  __syncthreads();
  float S = red[0][0] + red[1][0], SS = red[0][1] + red[1][1];
  float m = S * (1.0f / 128.0f);
  float v = SS * (1.0f / 128.0f) - m * m;
  float y = (g - m) * rsqrtf(v + EPS) * lnw[j] + lnb[j];
  H[n * HID + j] = f2bf(y);
}

// ------- K2: repack+convert weights to bf16 k-major in workspace -----------
// conv_w [i][co][ci][t] (fp32) -> convWb [i][t][ci][co] (bf16)   147456 elems
// ssm_in_W [k][j]  (fp32)      -> ssmWb  [k][j]         (bf16)    16384 elems
// out_W   [k][j]   (fp32)      -> outWb  [k][j]         (bf16)    16384 elems
#define PREP_TOTAL (3 * 3 * HID * HID + 2 * HID * HID)
__global__ __launch_bounds__(256) void k_prep(
    const float* __restrict__ conv_w, const float* __restrict__ ssm_W,
    const float* __restrict__ out_W, u16* __restrict__ dst) {
  int idx = blockIdx.x * 256 + threadIdx.x;
  if (idx >= PREP_TOTAL) return;
  if (idx < 3 * 3 * HID * HID) {
    int co = idx & 127;
    int ci = (idx >> 7) & 127;
    int it = idx >> 14;  // i*3 + t
    int tp = it % 3, li = it / 3;
    dst[idx] = f2bf(conv_w[((li * HID + co) * HID + ci) * 3 + tp]);
  } else {
    int r = idx - 3 * 3 * HID * HID;
    dst[idx] = f2bf(r < HID * HID ? ssm_W[r] : out_W[r - HID * HID]);
  }
}

// ---------------- K3 helpers ----------------
// acc[i][j] += sum_k A_t[r0+i][k] * X[k][c0+j+(t-1)*D]
// Ag: bf16 k-major [tap][k][r]. X has 4-col zero guards on both sides.
template <int TAPS, int D>
__device__ __forceinline__ void mm_stage(
    float (*acc)[8], const u16* __restrict__ Ag,
    u16 (*X)[136], u16 (*Ws)[32][128], int t, int c0, int r0) {
  for (int kc = 0; kc < 4; ++kc) {
    __syncthreads();  // prev readers of Ws / writers of X done
    for (int u = t; u < TAPS * 512; u += 256) {
      int tap = u >> 9, w = u & 511;
      ((uint4*)&Ws[tap][0][0])[w] =
          ((const uint4*)(Ag + tap * 16384 + kc * 4096))[w];
    }
    __syncthreads();
    for (int kk = 0; kk < 32; ++kk) {
      int k = kc * 32 + kk;
      uint4 bv0 = *(const uint4*)&X[k][c0];      // l-space cols c0-4 .. c0+3
      uint4 bv1 = *(const uint4*)&X[k][c0 + 8];  // l-space cols c0+4 .. c0+11
      float b[16];
      unp8(bv0, b);
      unp8(bv1, b + 8);
#pragma unroll
      for (int tap = 0; tap < TAPS; ++tap) {
        uint4 av = *(const uint4*)&Ws[tap][kk][r0];
        float a[8];
        unp8(av, a);
        const int off = 4 + (tap - 1) * D;  // TAPS=1 => off=4 (center)
#pragma unroll
        for (int i = 0; i < 8; ++i)
#pragma unroll
          for (int jj = 0; jj < 8; ++jj) acc[i][jj] += a[i] * b[off + jj];
      }
    }
  }
}

template <int D>
__device__ __forceinline__ void conv_layer(
    int li, int t, int c0, int r0, u16 (*X)[136], u16 (*Ws)[32][128],
    float (*red)[2][2], const u16* __restrict__ convW,
    const float* __restrict__ conv_b, const float* __restrict__ lnw,
    const float* __restrict__ lnb) {
  float acc[8][8];
#pragma unroll
  for (int i = 0; i < 8; ++i)
#pragma unroll
    for (int j = 0; j < 8; ++j) acc[i][j] = 0.f;
  mm_stage<3, D>(acc, convW + li * 3 * 16384, X, Ws, t, c0, r0);
  float bi[8];
#pragma unroll
  for (int i = 0; i < 8; ++i) bi[i] = conv_b[li * HID + r0 + i];
  __syncthreads();  // all X reads done before overwrite
#pragma unroll
  for (int i = 0; i < 8; ++i) {
    float v[8];
#pragma unroll
    for (int j = 0; j < 8; ++j) v[j] = gelu_exact(acc[i][j] + bi[i]);
    uint2 p0, p1;
    p0.x = pack2(v[0], v[1]); p0.y = pack2(v[2], v[3]);
    p1.x = pack2(v[4], v[5]); p1.y = pack2(v[6], v[7]);
    *(uint2*)&X[r0 + i][4 + c0] = p0;
    *(uint2*)&X[r0 + i][4 + c0 + 4] = p1;
  }
  __syncthreads();
  // LayerNorm over L (last axis); ln weights indexed by l
  int r = t >> 1, h = t & 1;
  float s = 0.f, ss = 0.f;
#pragma unroll
  for (int q = 0; q < 16; ++q) {
    uint2 v = *(const uint2*)&X[r][4 + 64 * h + q * 4];
    float f0 = bf2f((u16)(v.x & 0xffff)), f1 = bf2f((u16)(v.x >> 16));
    float f2 = bf2f((u16)(v.y & 0xffff)), f3 = bf2f((u16)(v.y >> 16));
    s += f0 + f1 + f2 + f3;
    ss += f0 * f0 + f1 * f1 + f2 * f2 + f3 * f3;
  }
  red[r][h][0] = s;
  red[r][h][1] = ss;
  __syncthreads();
  float S = red[r][0][0] + red[r][1][0];
  float SS = red[r][0][1] + red[r][1][1];
  float m = S * (1.0f / 128.0f);
  float var = SS * (1.0f / 128.0f) - m * m;
  float inv = rsqrtf(var + EPS);
#pragma unroll
  for (int q = 0; q < 16; ++q) {
    uint2 v = *(const uint2*)&X[r][4 + 64 * h + q * 4];
    float4 wv = *(const float4*)(lnw + li * HID + 64 * h + q * 4);
    float4 bv = *(const float4*)(lnb + li * HID + 64 * h + q * 4);
    float f0 = (bf2f((u16)(v.x & 0xffff)) - m) * inv * wv.x + bv.x;
    float f1 = (bf2f((u16)(v.x >> 16)) - m) * inv * wv.y + bv.y;
    float f2 = (bf2f((u16)(v.y & 0xffff)) - m) * inv * wv.z + bv.z;
    float f3 = (bf2f((u16)(v.y >> 16)) - m) * inv * wv.w + bv.w;
    uint2 o;
    o.x = pack2(f0, f1);
    o.y = pack2(f2, f3);
    *(uint2*)&X[r][4 + 64 * h + q * 4] = o;
  }
  __syncthreads();
}

// ---------------- K3: fused per-node pipeline ----------------
__global__ __launch_bounds__(256, 2) void k_main(
    const int* __restrict__ nidx, const int* __restrict__ nlen,
    const u16* __restrict__ Hg, const u16* __restrict__ ssmWb,
    const float* __restrict__ ssm_b, const u16* __restrict__ convW,
    const float* __restrict__ conv_b, const float* __restrict__ lnw,
    const float* __restrict__ lnb, const u16* __restrict__ outWb,
    const float* __restrict__ outb, const float* __restrict__ W1,
    const float* __restrict__ b1, const float* __restrict__ W2,
    const float* __restrict__ b2, float* __restrict__ out) {
  // X: rows = feature (k/ci/co), cols = guard(4) + l(128) + guard(4)
  __shared__ __align__(16) u16 X[128][136];
  __shared__ __align__(16) u16 Ws[3][32][128];
  __shared__ float red[128][2][2];
  __shared__ float pooled[128];
  __shared__ float z1s[64];

  int n = blockIdx.x;
  int t = threadIdx.x;
  int tc = t & 15, tr = t >> 4;
  int c0 = tc * 8, r0 = tr * 8;
  int len = nlen[n];

  // zero guard columns once (they stay zero across all stages)
  for (int q = t; q < 128 * 8; q += 256) {
    int row = q >> 3, g = q & 7;
    X[row][(g < 4) ? g : (128 + g)] = 0;
  }
  // gather: X[k][4+l] = H[nidx[l]][k] masked; 2 threads per l
  {
    int l = t >> 1, h = t & 1;
    int nb = nidx[n * MAXL + l];
    const uint4* Hrow = (const uint4*)(Hg + nb * HID + h * 64);
    bool valid = l < len;
#pragma unroll
    for (int mb = 0; mb < 8; ++mb) {
      uint4 v = Hrow[mb];
      if (!valid) { v.x = 0; v.y = 0; v.z = 0; v.w = 0; }
      int kb = h * 64 + mb * 8;
      X[kb + 0][4 + l] = (u16)(v.x & 0xffff);
      X[kb + 1][4 + l] = (u16)(v.x >> 16);
      X[kb + 2][4 + l] = (u16)(v.y & 0xffff);
      X[kb + 3][4 + l] = (u16)(v.y >> 16);
      X[kb + 4][4 + l] = (u16)(v.z & 0xffff);
      X[kb + 5][4 + l] = (u16)(v.z >> 16);
      X[kb + 6][4 + l] = (u16)(v.w & 0xffff);
      X[kb + 7][4 + l] = (u16)(v.w >> 16);
    }
  }

  // ---- S1: h = seq @ ssm_in_W + b, stored transposed as X[channel][l]
  {
    float acc[8][8];
#pragma unroll
    for (int i = 0; i < 8; ++i)
#pragma unroll
      for (int j = 0; j < 8; ++j) acc[i][j] = 0.f;
    mm_stage<1, 0>(acc, ssmWb, X, Ws, t, c0, r0);
    float bi[8];
#pragma unroll
    for (int i = 0; i < 8; ++i) bi[i] = ssm_b[r0 + i];
    __syncthreads();
#pragma unroll
    for (int i = 0; i < 8; ++i) {
      float v[8];
#pragma unroll
      for (int j = 0; j < 8; ++j) v[j] = acc[i][j] + bi[i];
      uint2 p0, p1;
      p0.x = pack2(v[0], v[1]); p0.y = pack2(v[2], v[3]);
      p1.x = pack2(v[4], v[5]); p1.y = pack2(v[6], v[7]);
      *(uint2*)&X[r0 + i][4 + c0] = p0;
      *(uint2*)&X[r0 + i][4 + c0 + 4] = p1;
    }
    __syncthreads();
  }

  // ---- 3 dilated conv layers (d = 1, 2, 4)
  conv_layer<1>(0, t, c0, r0, X, Ws, red, convW, conv_b, lnw, lnb);
  conv_layer<2>(1, t, c0, r0, X, Ws, red, convW, conv_b, lnw, lnb);
  conv_layer<4>(2, t, c0, r0, X, Ws, red, convW, conv_b, lnw, lnb);

  // ---- out projection + masked mean pool
  {
    float acc[8][8];
#pragma unroll
    for (int i = 0; i < 8; ++i)
#pragma unroll
      for (int j = 0; j < 8; ++j) acc[i][j] = 0.f;
    mm_stage<1, 0>(acc, outWb, X, Ws, t, c0, r0);
    float bi[8];
#pragma unroll
    for (int i = 0; i < 8; ++i) bi[i] = outb[r0 + i];
    __syncthreads();  // done reading X and Ws; reuse Ws as float scratch
    float* pp = (float*)&Ws[0][0][0];  // [128][16]
#pragma unroll
    for (int i = 0; i < 8; ++i) {
      float s = 0.f;
#pragma unroll
      for (int j = 0; j < 8; ++j) {
        int l = c0 + j;
        if (l < len) s += acc[i][j] + bi[i];
      }
      pp[(r0 + i) * 16 + tc] = s;
    }
    __syncthreads();
    if (t < 128) {
      float s = 0.f;
#pragma unroll
      for (int q = 0; q < 16; ++q) s += pp[t * 16 + q];
      float denom = (len > 0) ? (float)len : 1.0f;
      pooled[t] = s / denom;
    }
    __syncthreads();
  }

  // ---- classifier
  if (t < 64) {
    float s = b1[t];
#pragma unroll 4
    for (int c = 0; c < 128; ++c) s += pooled[c] * W1[c * 64 + t];
    z1s[t] = gelu_exact(s);
  }
  __syncthreads();
  if (t < 64) {
    float s = b2[t];
#pragma unroll 4
    for (int j = 0; j < 64; ++j) s += z1s[j] * W2[j * 64 + t];
    out[n * NCLS + t] = s;
  }
}

extern "C" void kernel_launch(void* const* d_in, const int* in_sizes, int n_in,
                              void* d_out, int out_size, void* d_ws,
                              size_t ws_size, hipStream_t stream) {
  const float* node_feat = (const float*)d_in[0];
  const int* nidx = (const int*)d_in[1];
  const int* nlen = (const int*)d_in[2];
  const float* local_W = (const float*)d_in[3];
  const float* local_b = (const float*)d_in[4];
  const float* local_ln_w = (const float*)d_in[5];
  const float* local_ln_b = (const float*)d_in[6];
  const float* ssm_W = (const float*)d_in[7];
  const float* ssm_b = (const float*)d_in[8];
  const float* conv_w = (const float*)d_in[9];
  const float* conv_b = (const float*)d_in[10];
  const float* lnw = (const float*)d_in[11];
  const float* lnb = (const float*)d_in[12];
  const float* outW = (const float*)d_in[13];
  const float* outb = (const float*)d_in[14];
  const float* W1 = (const float*)d_in[15];
  const float* b1 = (const float*)d_in[16];
  const float* W2 = (const float*)d_in[17];
  const float* b2 = (const float*)d_in[18];

  u16* Hws = (u16*)d_ws;            // 16384*128 bf16 = 4 MB
  u16* convWb = Hws + NN * HID;     // 147456 bf16
  u16* ssmWb = convWb + 3 * 3 * HID * HID;  // 16384 bf16
  u16* outWb = ssmWb + HID * HID;           // 16384 bf16

  k_local_encoder<<<NN, 128, 0, stream>>>(node_feat, local_W, local_b,
                                          local_ln_w, local_ln_b, Hws);
  k_prep<<<(PREP_TOTAL + 255) / 256, 256, 0, stream>>>(conv_w, ssm_W, outW,
                                                       convWb);
  k_main<<<NN, 256, 0, stream>>>(nidx, nlen, Hws, ssmWb, ssm_b, convWb, conv_b,
                                 lnw, lnb, outWb, outb, W1, b1, W2, b2,
                                 (float*)d_out);
}

// Round 3
// 2239.576 us; speedup vs baseline: 4.1200x; 4.1200x over previous
//
#include <hip/hip_runtime.h>
#include <hip/hip_bf16.h>
#include <math.h>

#define NN 16384
#define IN_DIM 256
#define HID 128
#define MAXL 128
#define NCLS 64
#define EPS 1e-5f

typedef unsigned short u16;
typedef unsigned int u32;
typedef __attribute__((ext_vector_type(8))) short short8;
typedef __attribute__((ext_vector_type(4))) float f32x4;

__device__ __forceinline__ float bf2f(u16 u) {
  union { u32 i; float f; } v; v.i = ((u32)u) << 16; return v.f;
}
__device__ __forceinline__ u16 f2bf(float f) {
  union { float f; u32 i; } v; v.f = f;
  u32 x = v.i;
  u32 r = (x + 0x7fffu + ((x >> 16) & 1u)) >> 16;
  return (u16)r;
}
__device__ __forceinline__ float gelu_exact(float x) {
  return 0.5f * x * (1.0f + erff(x * 0.70710678118654752440f));
}

// ---------------- K1: H = LN(GELU(node_feat @ local_W + b)), 8 nodes/block --
__global__ __launch_bounds__(128) void k_local_encoder(
    const float* __restrict__ node_feat, const float* __restrict__ local_W,
    const float* __restrict__ local_b, const float* __restrict__ lnw,
    const float* __restrict__ lnb, u16* __restrict__ H) {
  __shared__ float x[8][IN_DIM];
  __shared__ float red[8][2][2];
  int n0 = blockIdx.x * 8, j = threadIdx.x;
  for (int q = j; q < 8 * IN_DIM; q += 128)
    x[q >> 8][q & 255] = node_feat[n0 * IN_DIM + q];
  __syncthreads();
  float acc[8];
#pragma unroll
  for (int p = 0; p < 8; ++p) acc[p] = local_b[j];
  for (int k = 0; k < IN_DIM; ++k) {
    float w = local_W[k * HID + j];
#pragma unroll
    for (int p = 0; p < 8; ++p) acc[p] += x[p][k] * w;
  }
  float lw = lnw[j], lb = lnb[j];
  int wave = j >> 6;
  float g[8];
#pragma unroll
  for (int p = 0; p < 8; ++p) {
    g[p] = gelu_exact(acc[p]);
    float s = g[p], ss = g[p] * g[p];
#pragma unroll
    for (int o = 1; o < 64; o <<= 1) {
      s += __shfl_xor(s, o, 64);
      ss += __shfl_xor(ss, o, 64);
    }
    if ((j & 63) == 0) { red[p][wave][0] = s; red[p][wave][1] = ss; }
  }
  __syncthreads();
#pragma unroll
  for (int p = 0; p < 8; ++p) {
    float S = red[p][0][0] + red[p][1][0];
    float SS = red[p][0][1] + red[p][1][1];
    float m = S * (1.0f / 128.0f);
    float v = SS * (1.0f / 128.0f) - m * m;
    float y = (g[p] - m) * rsqrtf(v + EPS) * lw + lb;
    H[(n0 + p) * HID + j] = f2bf(y);
  }
}

// ------- K2: repack+convert weights to bf16, B-fragment-friendly order -----
// convWb2 idx = (li*4+kc)*12288 + tap*4096 + co*32 + cio  <- conv_w[li][co][kc*32+cio][tap]
// ssmWb2  idx = (kc*128+j)*32 + ko                        <- ssm_W[kc*32+ko][j]
// outWb2  same from out_W
#define CONV_ELEMS (3 * 4 * 3 * 128 * 32)  // 147456
#define PREP_TOTAL (CONV_ELEMS + 2 * HID * HID)
__global__ __launch_bounds__(256) void k_prep(
    const float* __restrict__ conv_w, const float* __restrict__ ssm_W,
    const float* __restrict__ out_W, u16* __restrict__ dst) {
  int idx = blockIdx.x * 256 + threadIdx.x;
  if (idx >= PREP_TOTAL) return;
  if (idx < CONV_ELEMS) {
    int cio = idx & 31;
    int co = (idx >> 5) & 127;
    int X = idx >> 12;
    int tap = X % 3, Y = X / 3;
    int kc = Y & 3, li = Y >> 2;
    int ci = kc * 32 + cio;
    dst[idx] = f2bf(conv_w[((li * HID + co) * HID + ci) * 3 + tap]);
  } else {
    int q2 = idx - CONV_ELEMS;
    int sel = q2 >> 14;             // 0 = ssm, 1 = out
    int r = q2 & 16383;
    int ko = r & 31, jj = (r >> 5) & 127, kc = r >> 12;
    const float* src = sel ? out_W : ssm_W;
    dst[idx] = f2bf(src[(kc * 32 + ko) * HID + jj]);
  }
}

// ---------------- K3: fused per-node MFMA pipeline ----------------
// S[l][c]: rows = l (4 guard rows each side), cols = channel (+8 pad)
// A-frag (m=l): lane m = lane&15, k = quad*8+j  -> ds_read_b128 of S row
// B-frag (n=co): Ws[co][tap*32 + quad*8]        -> ds_read_b128 of Ws row
// C/D: col co = lane&15, row l = quad*4 + reg
template <int TAPS, int D>
__device__ __forceinline__ void run_mfma(f32x4 (*acc)[4],
                                         const u16* __restrict__ Wg,
                                         u16 (*S)[136], u16 (*Ws)[104], int t,
                                         int li16, int quad, int lbase,
                                         int cbase) {
  for (int kc = 0; kc < 4; ++kc) {
    __syncthreads();  // prior S writes / Ws(red2) readers done
    for (int q = t; q < TAPS * 512; q += 256) {
      int tap = q >> 9, co = (q >> 2) & 127, c8 = q & 3;
      *(uint4*)&Ws[co][tap * 32 + c8 * 8] =
          *(const uint4*)(Wg + kc * (TAPS * 4096) + q * 8);
    }
    __syncthreads();
#pragma unroll
    for (int tap = 0; tap < TAPS; ++tap) {
      const int shift = (tap - 1) * D;
      short8 b[4], a[4];
#pragma unroll
      for (int j = 0; j < 4; ++j)
        b[j] = *(const short8*)&Ws[cbase + j * 16 + li16][tap * 32 + quad * 8];
#pragma unroll
      for (int i = 0; i < 4; ++i)
        a[i] = *(const short8*)&S[4 + lbase + i * 16 + li16 + shift]
                                 [kc * 32 + quad * 8];
#pragma unroll
      for (int i = 0; i < 4; ++i)
#pragma unroll
        for (int j = 0; j < 4; ++j)
          acc[i][j] =
              __builtin_amdgcn_mfma_f32_16x16x32_bf16(a[i], b[j], acc[i][j], 0, 0, 0);
    }
  }
}

__global__ __launch_bounds__(256, 2) void k_main(
    const int* __restrict__ nidx, const int* __restrict__ nlen,
    const u16* __restrict__ Hg, const u16* __restrict__ ssmWb2,
    const float* __restrict__ ssm_b, const u16* __restrict__ convWb2,
    const float* __restrict__ conv_b, const float* __restrict__ lnw,
    const float* __restrict__ lnb, const u16* __restrict__ outWb2,
    const float* __restrict__ out_b, const float* __restrict__ W1,
    const float* __restrict__ b1, const float* __restrict__ W2,
    const float* __restrict__ b2, float* __restrict__ out) {
  __shared__ __align__(16) u16 S[136][136];     // 36,992 B
  __shared__ __align__(16) u16 Ws[128][104];    // 26,624 B (aliased in epilogues)
  float* red2 = (float*)&Ws[0][0];              // [128][4]
  float* lnc = (float*)&Ws[0][0] + 512;         // float2[128] as float[256]
  float* pooled = (float*)&Ws[0][0] + 768;      // [128]
  float* z1s = (float*)&Ws[0][0] + 896;         // [64]

  int n = blockIdx.x;
  int t = threadIdx.x;
  int lane = t & 63, w = t >> 6;
  int li16 = lane & 15, quad = lane >> 4;
  int lbase = (w >> 1) * 64, cbase = (w & 1) * 64;
  int rowhalf = w >> 1;
  int len = nlen[n];
  int cols[4];
#pragma unroll
  for (int jt = 0; jt < 4; ++jt) cols[jt] = cbase + jt * 16 + li16;

  // zero guard rows (stay zero across all stages)
  if (t < 136) {
    int g = t / 17, c16 = t % 17;
    int row = (g < 4) ? g : 128 + g;  // rows 0..3, 132..135
    uint4 z; z.x = 0; z.y = 0; z.z = 0; z.w = 0;
    ((uint4*)&S[row][0])[c16] = z;
  }
  // gather: S[4+l][:] = H[nidx[l]] masked; 2 threads per l, row-contiguous
  {
    int l = t >> 1, h = t & 1;
    int nb = nidx[n * MAXL + l];
    bool valid = l < len;
    const uint4* Hrow = (const uint4*)(Hg + nb * HID + h * 64);
    uint4* drow = (uint4*)&S[4 + l][h * 64];
#pragma unroll
    for (int mb = 0; mb < 8; ++mb) {
      uint4 v = Hrow[mb];
      if (!valid) { v.x = 0; v.y = 0; v.z = 0; v.w = 0; }
      drow[mb] = v;
    }
  }

  f32x4 acc[4][4];

  // ---- S1: h = seq @ ssm_in_W + b (no activation)
#pragma unroll
  for (int i = 0; i < 4; ++i)
#pragma unroll
    for (int j = 0; j < 4; ++j) acc[i][j] = (f32x4){0.f, 0.f, 0.f, 0.f};
  run_mfma<1, 0>(acc, ssmWb2, S, Ws, t, li16, quad, lbase, cbase);
  __syncthreads();
#pragma unroll
  for (int jt = 0; jt < 4; ++jt) {
    float bias = ssm_b[cols[jt]];
#pragma unroll
    for (int i = 0; i < 4; ++i)
#pragma unroll
      for (int r = 0; r < 4; ++r) {
        int l = lbase + i * 16 + quad * 4 + r;
        S[4 + l][cols[jt]] = f2bf(acc[i][jt][r] + bias);
      }
  }

  // ---- 3 dilated conv layers: GEMM -> +bias -> GELU -> LN over l
#pragma unroll
  for (int li = 0; li < 3; ++li) {
#pragma unroll
    for (int i = 0; i < 4; ++i)
#pragma unroll
      for (int j = 0; j < 4; ++j) acc[i][j] = (f32x4){0.f, 0.f, 0.f, 0.f};
    if (li == 0)
      run_mfma<3, 1>(acc, convWb2, S, Ws, t, li16, quad, lbase, cbase);
    else if (li == 1)
      run_mfma<3, 2>(acc, convWb2 + 49152, S, Ws, t, li16, quad, lbase, cbase);
    else
      run_mfma<3, 4>(acc, convWb2 + 98304, S, Ws, t, li16, quad, lbase, cbase);
    __syncthreads();  // all frag reads done; Ws reusable as red2/lnc
    if (t < 128) {
      lnc[2 * t] = lnw[li * HID + t];
      lnc[2 * t + 1] = lnb[li * HID + t];
    }
#pragma unroll
    for (int jt = 0; jt < 4; ++jt) {
      float bias = conv_b[li * HID + cols[jt]];
      float s = 0.f, ss = 0.f;
#pragma unroll
      for (int i = 0; i < 4; ++i)
#pragma unroll
        for (int r = 0; r < 4; ++r) {
          float g = gelu_exact(acc[i][jt][r] + bias);
          acc[i][jt][r] = g;
          s += g;
          ss += g * g;
        }
      s += __shfl_xor(s, 16, 64); s += __shfl_xor(s, 32, 64);
      ss += __shfl_xor(ss, 16, 64); ss += __shfl_xor(ss, 32, 64);
      if (quad == 0) {
        red2[cols[jt] * 4 + rowhalf] = s;
        red2[cols[jt] * 4 + 2 + rowhalf] = ss;
      }
    }
    __syncthreads();
    float m4[4], inv4[4];
#pragma unroll
    for (int jt = 0; jt < 4; ++jt) {
      float S_ = red2[cols[jt] * 4 + 0] + red2[cols[jt] * 4 + 1];
      float SS_ = red2[cols[jt] * 4 + 2] + red2[cols[jt] * 4 + 3];
      float m = S_ * (1.0f / 128.0f);
      float var = SS_ * (1.0f / 128.0f) - m * m;
      m4[jt] = m;
      inv4[jt] = rsqrtf(var + EPS);
    }
#pragma unroll
    for (int i = 0; i < 4; ++i)
#pragma unroll
      for (int r = 0; r < 4; ++r) {
        int l = lbase + i * 16 + quad * 4 + r;
        float lw = lnc[2 * l], lb = lnc[2 * l + 1];
#pragma unroll
        for (int jt = 0; jt < 4; ++jt)
          S[4 + l][cols[jt]] =
              f2bf((acc[i][jt][r] - m4[jt]) * inv4[jt] * lw + lb);
      }
  }

  // ---- out projection + masked mean pool
#pragma unroll
  for (int i = 0; i < 4; ++i)
#pragma unroll
    for (int j = 0; j < 4; ++j) acc[i][j] = (f32x4){0.f, 0.f, 0.f, 0.f};
  run_mfma<1, 0>(acc, outWb2, S, Ws, t, li16, quad, lbase, cbase);
  __syncthreads();
#pragma unroll
  for (int jt = 0; jt < 4; ++jt) {
    float s = 0.f;
#pragma unroll
    for (int i = 0; i < 4; ++i)
#pragma unroll
      for (int r = 0; r < 4; ++r) {
        int l = lbase + i * 16 + quad * 4 + r;
        if (l < len) s += acc[i][jt][r];
      }
    s += __shfl_xor(s, 16, 64); s += __shfl_xor(s, 32, 64);
    if (quad == 0) red2[cols[jt] * 4 + rowhalf] = s;
  }
  __syncthreads();
  if (t < 128) {
    float tot = red2[t * 4] + red2[t * 4 + 1];
    pooled[t] = (len > 0) ? (tot / (float)len + out_b[t]) : 0.f;
  }
  __syncthreads();
  // ---- classifier
  if (t < 64) {
    float s = b1[t];
#pragma unroll 4
    for (int c = 0; c < 128; ++c) s += pooled[c] * W1[c * 64 + t];
    z1s[t] = gelu_exact(s);
  }
  __syncthreads();
  if (t < 64) {
    float s = b2[t];
#pragma unroll 4
    for (int j = 0; j < 64; ++j) s += z1s[j] * W2[j * 64 + t];
    out[n * NCLS + t] = s;
  }
}

extern "C" void kernel_launch(void* const* d_in, const int* in_sizes, int n_in,
                              void* d_out, int out_size, void* d_ws,
                              size_t ws_size, hipStream_t stream) {
  const float* node_feat = (const float*)d_in[0];
  const int* nidx = (const int*)d_in[1];
  const int* nlen = (const int*)d_in[2];
  const float* local_W = (const float*)d_in[3];
  const float* local_b = (const float*)d_in[4];
  const float* local_ln_w = (const float*)d_in[5];
  const float* local_ln_b = (const float*)d_in[6];
  const float* ssm_W = (const float*)d_in[7];
  const float* ssm_b = (const float*)d_in[8];
  const float* conv_w = (const float*)d_in[9];
  const float* conv_b = (const float*)d_in[10];
  const float* lnw = (const float*)d_in[11];
  const float* lnb = (const float*)d_in[12];
  const float* outW = (const float*)d_in[13];
  const float* outb = (const float*)d_in[14];
  const float* W1 = (const float*)d_in[15];
  const float* b1 = (const float*)d_in[16];
  const float* W2 = (const float*)d_in[17];
  const float* b2 = (const float*)d_in[18];

  u16* Hws = (u16*)d_ws;                     // 16384*128 bf16
  u16* convWb2 = Hws + NN * HID;             // 147456
  u16* ssmWb2 = convWb2 + CONV_ELEMS;        // 16384
  u16* outWb2 = ssmWb2 + HID * HID;          // 16384

  k_local_encoder<<<NN / 8, 128, 0, stream>>>(node_feat, local_W, local_b,
                                              local_ln_w, local_ln_b, Hws);
  k_prep<<<(PREP_TOTAL + 255) / 256, 256, 0, stream>>>(conv_w, ssm_W, outW,
                                                       convWb2);
  k_main<<<NN, 256, 0, stream>>>(nidx, nlen, Hws, ssmWb2, ssm_b, convWb2,
                                 conv_b, lnw, lnb, outWb2, outb, W1, b1, W2,
                                 b2, (float*)d_out);
}

// Round 4
// 2143.507 us; speedup vs baseline: 4.3046x; 1.0448x over previous
//
#include <hip/hip_runtime.h>
#include <hip/hip_bf16.h>
#include <math.h>

#define NN 16384
#define IN_DIM 256
#define HID 128
#define MAXL 128
#define NCLS 64
#define EPS 1e-5f

typedef unsigned short u16;
typedef unsigned int u32;
typedef __attribute__((ext_vector_type(8))) short short8;
typedef __attribute__((ext_vector_type(4))) float f32x4;

// scratch layout (floats)
#define CVEC 0
#define GV 128
#define BV 256
#define RS0 384
#define RS1 512
#define RSS0 640
#define RSS1 768
#define SCR_N 896

__device__ __forceinline__ float bf2f(u16 u) {
  union { u32 i; float f; } v; v.i = ((u32)u) << 16; return v.f;
}
__device__ __forceinline__ u16 f2bf(float f) {
  union { float f; u32 i; } v; v.f = f;
  u32 x = v.i;
  u32 r = (x + 0x7fffu + ((x >> 16) & 1u)) >> 16;
  return (u16)r;
}
__device__ __forceinline__ u32 pack2(float a, float b) {
  return (u32)f2bf(a) | ((u32)f2bf(b) << 16);
}
__device__ __forceinline__ float gelu_exact(float x) {
  return 0.5f * x * (1.0f + erff(x * 0.70710678118654752440f));
}
// x in [0, ~169]
__device__ __forceinline__ int mod17(int x) { return x - 17 * ((x * 241) >> 12); }

// ---------------- K1: H = LN(GELU(node_feat @ local_W + b)), 8 nodes/block --
__global__ __launch_bounds__(128) void k_local_encoder(
    const float* __restrict__ node_feat, const float* __restrict__ local_W,
    const float* __restrict__ local_b, const float* __restrict__ lnw,
    const float* __restrict__ lnb, u16* __restrict__ H) {
  __shared__ float x[8][IN_DIM];
  __shared__ float red[8][2][2];
  int n0 = blockIdx.x * 8, j = threadIdx.x;
  for (int q = j; q < 8 * IN_DIM; q += 128)
    x[q >> 8][q & 255] = node_feat[n0 * IN_DIM + q];
  __syncthreads();
  float acc[8];
#pragma unroll
  for (int p = 0; p < 8; ++p) acc[p] = local_b[j];
  for (int k = 0; k < IN_DIM; ++k) {
    float w = local_W[k * HID + j];
#pragma unroll
    for (int p = 0; p < 8; ++p) acc[p] += x[p][k] * w;
  }
  float lw = lnw[j], lb = lnb[j];
  int wave = j >> 6;
  float g[8];
#pragma unroll
  for (int p = 0; p < 8; ++p) {
    g[p] = gelu_exact(acc[p]);
    float s = g[p], ss = g[p] * g[p];
#pragma unroll
    for (int o = 1; o < 64; o <<= 1) {
      s += __shfl_xor(s, o, 64);
      ss += __shfl_xor(ss, o, 64);
    }
    if ((j & 63) == 0) { red[p][wave][0] = s; red[p][wave][1] = ss; }
  }
  __syncthreads();
#pragma unroll
  for (int p = 0; p < 8; ++p) {
    float S = red[p][0][0] + red[p][1][0];
    float SS = red[p][0][1] + red[p][1][1];
    float m = S * (1.0f / 128.0f);
    float v = SS * (1.0f / 128.0f) - m * m;
    float y = (g[p] - m) * rsqrtf(v + EPS) * lw + lb;
    H[(n0 + p) * HID + j] = f2bf(y);
  }
}

// ------- K2: repack weights to bf16, A-fragment (wave-coalesced) order -----
// chunk(li,kc,tap,g) = 512 elems laid [li16(16)][quad(4)][e(8)]:
//   elem = W[co = g*16+li16][ci = kc*32+quad*8+e]  (per tap for conv)
#define CONV_ELEMS (3 * 4 * 3 * 8 * 512)  // 147456
#define PREP_TOTAL (CONV_ELEMS + 2 * HID * HID)
__global__ __launch_bounds__(256) void k_prep(
    const float* __restrict__ conv_w, const float* __restrict__ ssm_W,
    const float* __restrict__ out_W, u16* __restrict__ dst) {
  int idx = blockIdx.x * 256 + threadIdx.x;
  if (idx >= PREP_TOTAL) return;
  if (idx < CONV_ELEMS) {
    int e = idx & 7, quad = (idx >> 3) & 3, li16 = (idx >> 5) & 15,
        g = (idx >> 9) & 7;
    int rest = idx >> 12;  // 0..35 = ((li*4+kc)*3+tap)
    int tap = rest % 3, kcli = rest / 3;
    int kc = kcli & 3, li = kcli >> 2;
    int co = g * 16 + li16, ci = kc * 32 + quad * 8 + e;
    dst[idx] = f2bf(conv_w[((li * HID + co) * HID + ci) * 3 + tap]);
  } else {
    int r = idx - CONV_ELEMS;
    int sel = r >> 14;  // 0 = ssm, 1 = out
    r &= 16383;
    int e = r & 7, quad = (r >> 3) & 3, li16 = (r >> 5) & 15, g = (r >> 9) & 7;
    int kc = r >> 12;
    const float* src = sel ? out_W : ssm_W;
    dst[idx] = f2bf(src[(kc * 32 + quad * 8 + e) * HID + g * 16 + li16]);
  }
}

// ---------------- K3 GEMM: D[co][l] = sum_ci,tap W[co][ci] * S[l+shift][ci] --
// w_frag (A): lane m=li16 -> co, k = quad*8+e  -> coalesced global chunk
// x_frag (B): lane n=li16 -> l,  k = quad*8+e  -> ds_read_b128 of S row
// C/D: lane = l (li16), regs = co (quad*4 + r, tile i)
template <int TAPS, int DIL>
__device__ __forceinline__ void run_gemm(f32x4 (*acc)[4],
                                         const u16* __restrict__ Wg,
                                         const u16* __restrict__ S, int li16,
                                         int quad, int lbase, int cbase) {
  int lrow0 = 4 + lbase + li16;
  const u16* wbase = Wg + (cbase >> 4) * 512 + li16 * 32 + quad * 8;
  for (int kc = 0; kc < 4; ++kc) {
#pragma unroll
    for (int tap = 0; tap < TAPS; ++tap) {
      const int shift = (TAPS == 3) ? (tap - 1) * DIL : 0;
      const u16* wp = wbase + (kc * TAPS + tap) * 4096;
      short8 a[4];
#pragma unroll
      for (int i = 0; i < 4; ++i) a[i] = *(const short8*)(wp + i * 512);
      int c8 = kc * 4 + quad;
      int row0 = lrow0 + shift;
      int m0 = mod17(c8 + row0);
      short8 b[4];
#pragma unroll
      for (int j = 0; j < 4; ++j) {
        int mj = m0 - j;
        mj += (mj < 0) ? 17 : 0;
        b[j] = *(const short8*)&S[(row0 + 16 * j) * 136 + mj * 8];
      }
#pragma unroll
      for (int i = 0; i < 4; ++i)
#pragma unroll
        for (int j = 0; j < 4; ++j)
          acc[i][j] = __builtin_amdgcn_mfma_f32_16x16x32_bf16(a[i], b[j],
                                                              acc[i][j], 0, 0, 0);
    }
  }
}

__device__ __forceinline__ void zero_acc(f32x4 (*acc)[4]) {
#pragma unroll
  for (int i = 0; i < 4; ++i)
#pragma unroll
    for (int j = 0; j < 4; ++j) acc[i][j] = (f32x4){0.f, 0.f, 0.f, 0.f};
}

template <int DIL>
__device__ __forceinline__ void conv_stage(
    f32x4 (*acc)[4], const u16* __restrict__ Wg, u16* S, float* scr, int t,
    int li16, int quad, int lbase, int cbase, int lhalf,
    const float* __restrict__ cb, const float* __restrict__ gw,
    const float* __restrict__ gb) {
  if (t < 128) {
    scr[CVEC + t] = cb[t];
    scr[GV + t] = gw[t];
    scr[BV + t] = gb[t];
  }
  zero_acc(acc);
  run_gemm<3, DIL>(acc, Wg, S, li16, quad, lbase, cbase);
  __syncthreads();  // S reads done; cvec/gv/bv visible
  // bias + gelu, channel partial sums
#pragma unroll
  for (int i = 0; i < 4; ++i) {
    f32x4 b4 = *(const f32x4*)&scr[CVEC + cbase + i * 16 + quad * 4];
    f32x4 s = (f32x4){0.f, 0.f, 0.f, 0.f}, ss = s;
#pragma unroll
    for (int j = 0; j < 4; ++j) {
#pragma unroll
      for (int r = 0; r < 4; ++r) {
        float g = gelu_exact(acc[i][j][r] + b4[r]);
        acc[i][j][r] = g;
      }
      s += acc[i][j];
      ss += acc[i][j] * acc[i][j];
    }
#pragma unroll
    for (int r = 0; r < 4; ++r) {
      float sv = s[r], sq = ss[r];
      sv += __shfl_xor(sv, 1, 64); sq += __shfl_xor(sq, 1, 64);
      sv += __shfl_xor(sv, 2, 64); sq += __shfl_xor(sq, 2, 64);
      sv += __shfl_xor(sv, 4, 64); sq += __shfl_xor(sq, 4, 64);
      sv += __shfl_xor(sv, 8, 64); sq += __shfl_xor(sq, 8, 64);
      if (li16 == 0) {
        int co = cbase + 16 * i + quad * 4 + r;
        scr[(lhalf ? RS1 : RS0) + co] = sv;
        scr[(lhalf ? RSS1 : RSS0) + co] = sq;
      }
    }
  }
  __syncthreads();
  f32x4 m4[4], inv4[4];
#pragma unroll
  for (int i = 0; i < 4; ++i) {
    int co0 = cbase + 16 * i + quad * 4;
    f32x4 s0 = *(const f32x4*)&scr[RS0 + co0];
    f32x4 s1 = *(const f32x4*)&scr[RS1 + co0];
    f32x4 q0 = *(const f32x4*)&scr[RSS0 + co0];
    f32x4 q1 = *(const f32x4*)&scr[RSS1 + co0];
    f32x4 m = (s0 + s1) * (1.0f / 128.0f);
    f32x4 v = (q0 + q1) * (1.0f / 128.0f) - m * m;
    m4[i] = m;
#pragma unroll
    for (int r = 0; r < 4; ++r) inv4[i][r] = rsqrtf(v[r] + EPS);
  }
#pragma unroll
  for (int j = 0; j < 4; ++j) {
    int lloc = lbase + 16 * j + li16;
    int row = 4 + lloc;
    float gl = scr[GV + lloc], bl = scr[BV + lloc];
#pragma unroll
    for (int i = 0; i < 4; ++i) {
      int c8 = (cbase >> 3) + 2 * i + (quad >> 1);
      int phys = mod17(c8 + row);
      float y0 = (acc[i][j][0] - m4[i][0]) * inv4[i][0] * gl + bl;
      float y1 = (acc[i][j][1] - m4[i][1]) * inv4[i][1] * gl + bl;
      float y2 = (acc[i][j][2] - m4[i][2]) * inv4[i][2] * gl + bl;
      float y3 = (acc[i][j][3] - m4[i][3]) * inv4[i][3] * gl + bl;
      uint2 pk;
      pk.x = pack2(y0, y1);
      pk.y = pack2(y2, y3);
      *(uint2*)&S[row * 136 + phys * 8 + (quad & 1) * 4] = pk;
    }
  }
  __syncthreads();
}

__global__ __launch_bounds__(256, 4) void k_main(
    const int* __restrict__ nidx, const int* __restrict__ nlen,
    const u16* __restrict__ Hg, const u16* __restrict__ ssmW3,
    const float* __restrict__ ssm_b, const u16* __restrict__ convW3,
    const float* __restrict__ conv_b, const float* __restrict__ lnw,
    const float* __restrict__ lnb, const u16* __restrict__ outW3,
    const float* __restrict__ out_b, const float* __restrict__ W1,
    const float* __restrict__ b1, const float* __restrict__ W2,
    const float* __restrict__ b2, float* __restrict__ out) {
  __shared__ __align__(16) u16 S[136 * 136];
  __shared__ __align__(16) float scr[SCR_N];

  int n = blockIdx.x, t = threadIdx.x;
  int lane = t & 63, w = t >> 6;
  int li16 = lane & 15, quad = lane >> 4;
  int cbase = (w & 1) * 64, lbase = (w >> 1) * 64, lhalf = w >> 1;
  int len = nlen[n];

  // zero guard rows (all 17 chunks)
  if (t < 136) {
    int g = t / 17, c = t % 17;
    int row = (g < 4) ? g : 128 + g;
    uint4 z; z.x = 0; z.y = 0; z.z = 0; z.w = 0;
    *(uint4*)&S[row * 136 + c * 8] = z;
  }
  // gather: S row (4+l) = H[nidx[l]] masked, rotation-swizzled chunks
  {
    int l = t >> 1, h = t & 1;
    int nb = nidx[n * MAXL + l];
    bool valid = l < len;
    const uint4* Hrow = (const uint4*)(Hg + nb * HID + h * 64);
    int row = 4 + l;
#pragma unroll
    for (int mb = 0; mb < 8; ++mb) {
      uint4 v = Hrow[mb];
      if (!valid) { v.x = 0; v.y = 0; v.z = 0; v.w = 0; }
      int c8 = h * 8 + mb;
      int phys = mod17(c8 + row);
      *(uint4*)&S[row * 136 + phys * 8] = v;
    }
  }
  if (t < 128) scr[CVEC + t] = ssm_b[t];
  __syncthreads();

  f32x4 acc[4][4];

  // ---- S1: D = ssm_W^T · X  (+bias)
  zero_acc(acc);
  run_gemm<1, 0>(acc, ssmW3, S, li16, quad, lbase, cbase);
  __syncthreads();
#pragma unroll
  for (int i = 0; i < 4; ++i) {
    f32x4 b4 = *(const f32x4*)&scr[CVEC + cbase + i * 16 + quad * 4];
#pragma unroll
    for (int j = 0; j < 4; ++j) {
      int row = 4 + lbase + 16 * j + li16;
      int c8 = (cbase >> 3) + 2 * i + (quad >> 1);
      int phys = mod17(c8 + row);
      uint2 pk;
      pk.x = pack2(acc[i][j][0] + b4[0], acc[i][j][1] + b4[1]);
      pk.y = pack2(acc[i][j][2] + b4[2], acc[i][j][3] + b4[3]);
      *(uint2*)&S[row * 136 + phys * 8 + (quad & 1) * 4] = pk;
    }
  }
  __syncthreads();

  // ---- 3 dilated conv layers
  conv_stage<1>(acc, convW3, S, scr, t, li16, quad, lbase, cbase, lhalf,
                conv_b, lnw, lnb);
  conv_stage<2>(acc, convW3 + 49152, S, scr, t, li16, quad, lbase, cbase,
                lhalf, conv_b + HID, lnw + HID, lnb + HID);
  conv_stage<4>(acc, convW3 + 98304, S, scr, t, li16, quad, lbase, cbase,
                lhalf, conv_b + 2 * HID, lnw + 2 * HID, lnb + 2 * HID);

  // ---- out projection + masked mean pool
  zero_acc(acc);
  run_gemm<1, 0>(acc, outW3, S, li16, quad, lbase, cbase);
  __syncthreads();
#pragma unroll
  for (int i = 0; i < 4; ++i) {
    f32x4 s = (f32x4){0.f, 0.f, 0.f, 0.f};
#pragma unroll
    for (int j = 0; j < 4; ++j) {
      int lloc = lbase + 16 * j + li16;
      if (lloc < len) s += acc[i][j];
    }
#pragma unroll
    for (int r = 0; r < 4; ++r) {
      float sv = s[r];
      sv += __shfl_xor(sv, 1, 64);
      sv += __shfl_xor(sv, 2, 64);
      sv += __shfl_xor(sv, 4, 64);
      sv += __shfl_xor(sv, 8, 64);
      if (li16 == 0) {
        int co = cbase + 16 * i + quad * 4 + r;
        scr[(lhalf ? RS1 : RS0) + co] = sv;
      }
    }
  }
  __syncthreads();
  if (t < 128) {
    float tot = scr[RS0 + t] + scr[RS1 + t];
    scr[CVEC + t] = (len > 0) ? (tot / (float)len + out_b[t]) : 0.f;
  }
  __syncthreads();
  // ---- classifier (parallel over 4 partials)
  {
    int part = t >> 6, j = t & 63;
    float s = 0.f;
    int c0 = part * 32;
#pragma unroll 8
    for (int c = c0; c < c0 + 32; ++c) s += scr[CVEC + c] * W1[c * 64 + j];
    scr[RS0 + j * 4 + part] = s;
  }
  __syncthreads();
  if (t < 64) {
    float z = b1[t] + scr[RS0 + t * 4] + scr[RS0 + t * 4 + 1] +
              scr[RS0 + t * 4 + 2] + scr[RS0 + t * 4 + 3];
    scr[GV + t] = gelu_exact(z);
  }
  __syncthreads();
  {
    int part = t >> 6, j = t & 63;
    float s = 0.f;
    int c0 = part * 16;
#pragma unroll 8
    for (int c = c0; c < c0 + 16; ++c) s += scr[GV + c] * W2[c * 64 + j];
    scr[RS0 + j * 4 + part] = s;
  }
  __syncthreads();
  if (t < 64) {
    out[n * NCLS + t] = b2[t] + scr[RS0 + t * 4] + scr[RS0 + t * 4 + 1] +
                        scr[RS0 + t * 4 + 2] + scr[RS0 + t * 4 + 3];
  }
}

extern "C" void kernel_launch(void* const* d_in, const int* in_sizes, int n_in,
                              void* d_out, int out_size, void* d_ws,
                              size_t ws_size, hipStream_t stream) {
  const float* node_feat = (const float*)d_in[0];
  const int* nidx = (const int*)d_in[1];
  const int* nlen = (const int*)d_in[2];
  const float* local_W = (const float*)d_in[3];
  const float* local_b = (const float*)d_in[4];
  const float* local_ln_w = (const float*)d_in[5];
  const float* local_ln_b = (const float*)d_in[6];
  const float* ssm_W = (const float*)d_in[7];
  const float* ssm_b = (const float*)d_in[8];
  const float* conv_w = (const float*)d_in[9];
  const float* conv_b = (const float*)d_in[10];
  const float* lnw = (const float*)d_in[11];
  const float* lnb = (const float*)d_in[12];
  const float* outW = (const float*)d_in[13];
  const float* outb = (const float*)d_in[14];
  const float* W1 = (const float*)d_in[15];
  const float* b1 = (const float*)d_in[16];
  const float* W2 = (const float*)d_in[17];
  const float* b2 = (const float*)d_in[18];

  u16* Hws = (u16*)d_ws;                // 16384*128 bf16
  u16* convW3 = Hws + NN * HID;         // 147456
  u16* ssmW3 = convW3 + CONV_ELEMS;     // 16384
  u16* outW3 = ssmW3 + HID * HID;       // 16384

  k_local_encoder<<<NN / 8, 128, 0, stream>>>(node_feat, local_W, local_b,
                                              local_ln_w, local_ln_b, Hws);
  k_prep<<<(PREP_TOTAL + 255) / 256, 256, 0, stream>>>(conv_w, ssm_W, outW,
                                                       convW3);
  k_main<<<NN, 256, 0, stream>>>(nidx, nlen, Hws, ssmW3, ssm_b, convW3, conv_b,
                                 lnw, lnb, outW3, outb, W1, b1, W2, b2,
                                 (float*)d_out);
}

// Round 5
// 1711.946 us; speedup vs baseline: 5.3898x; 1.2521x over previous
//
#include <hip/hip_runtime.h>
#include <hip/hip_bf16.h>
#include <math.h>

#define NN 16384
#define IN_DIM 256
#define HID 128
#define MAXL 128
#define NCLS 64
#define EPS 1e-5f

typedef unsigned short u16;
typedef unsigned int u32;
typedef __attribute__((ext_vector_type(8))) short short8;
typedef __attribute__((ext_vector_type(4))) float f32x4;

// scratch layout (floats)
#define CVEC 0
#define GV 128
#define BV 256
#define RS0 384
#define SCR_N 640

__device__ __forceinline__ float bf2f(u16 u) {
  union { u32 i; float f; } v; v.i = ((u32)u) << 16; return v.f;
}
__device__ __forceinline__ u16 f2bf(float f) {
  union { float f; u32 i; } v; v.f = f;
  u32 x = v.i;
  u32 r = (x + 0x7fffu + ((x >> 16) & 1u)) >> 16;
  return (u16)r;
}
__device__ __forceinline__ u32 pack2(float a, float b) {
  return (u32)f2bf(a) | ((u32)f2bf(b) << 16);
}
__device__ __forceinline__ float gelu_exact(float x) {
  return 0.5f * x * (1.0f + erff(x * 0.70710678118654752440f));
}
// x in [0, ~169]
__device__ __forceinline__ int mod17(int x) { return x - 17 * ((x * 241) >> 12); }

// ---------------- K1: H = LN(GELU(node_feat @ local_W + b)), 8 nodes/block --
__global__ __launch_bounds__(128) void k_local_encoder(
    const float* __restrict__ node_feat, const float* __restrict__ local_W,
    const float* __restrict__ local_b, const float* __restrict__ lnw,
    const float* __restrict__ lnb, u16* __restrict__ H) {
  __shared__ float x[8][IN_DIM];
  __shared__ float red[8][2][2];
  int n0 = blockIdx.x * 8, j = threadIdx.x;
  for (int q = j; q < 8 * IN_DIM; q += 128)
    x[q >> 8][q & 255] = node_feat[n0 * IN_DIM + q];
  __syncthreads();
  float acc[8];
#pragma unroll
  for (int p = 0; p < 8; ++p) acc[p] = local_b[j];
  for (int k = 0; k < IN_DIM; ++k) {
    float w = local_W[k * HID + j];
#pragma unroll
    for (int p = 0; p < 8; ++p) acc[p] += x[p][k] * w;
  }
  float lw = lnw[j], lb = lnb[j];
  int wave = j >> 6;
  float g[8];
#pragma unroll
  for (int p = 0; p < 8; ++p) {
    g[p] = gelu_exact(acc[p]);
    float s = g[p], ss = g[p] * g[p];
#pragma unroll
    for (int o = 1; o < 64; o <<= 1) {
      s += __shfl_xor(s, o, 64);
      ss += __shfl_xor(ss, o, 64);
    }
    if ((j & 63) == 0) { red[p][wave][0] = s; red[p][wave][1] = ss; }
  }
  __syncthreads();
#pragma unroll
  for (int p = 0; p < 8; ++p) {
    float S = red[p][0][0] + red[p][1][0];
    float SS = red[p][0][1] + red[p][1][1];
    float m = S * (1.0f / 128.0f);
    float v = SS * (1.0f / 128.0f) - m * m;
    float y = (g[p] - m) * rsqrtf(v + EPS) * lw + lb;
    H[(n0 + p) * HID + j] = f2bf(y);
  }
}

// ------- K2: repack weights to bf16, A-fragment (wave-coalesced) order -----
// chunk(li,kc,tap,g) = 512 elems laid [li16(16)][quad(4)][e(8)]:
//   elem = W[co = g*16+li16][ci = kc*32+quad*8+e]  (per tap for conv)
#define CONV_ELEMS (3 * 4 * 3 * 8 * 512)  // 147456
#define PREP_TOTAL (CONV_ELEMS + 2 * HID * HID)
__global__ __launch_bounds__(256) void k_prep(
    const float* __restrict__ conv_w, const float* __restrict__ ssm_W,
    const float* __restrict__ out_W, u16* __restrict__ dst) {
  int idx = blockIdx.x * 256 + threadIdx.x;
  if (idx >= PREP_TOTAL) return;
  if (idx < CONV_ELEMS) {
    int e = idx & 7, quad = (idx >> 3) & 3, li16 = (idx >> 5) & 15,
        g = (idx >> 9) & 7;
    int rest = idx >> 12;  // 0..35 = ((li*4+kc)*3+tap)
    int tap = rest % 3, kcli = rest / 3;
    int kc = kcli & 3, li = kcli >> 2;
    int co = g * 16 + li16, ci = kc * 32 + quad * 8 + e;
    dst[idx] = f2bf(conv_w[((li * HID + co) * HID + ci) * 3 + tap]);
  } else {
    int r = idx - CONV_ELEMS;
    int sel = r >> 14;  // 0 = ssm, 1 = out
    r &= 16383;
    int e = r & 7, quad = (r >> 3) & 3, li16 = (r >> 5) & 15, g = (r >> 9) & 7;
    int kc = r >> 12;
    const float* src = sel ? out_W : ssm_W;
    dst[idx] = f2bf(src[(kc * 32 + quad * 8 + e) * HID + g * 16 + li16]);
  }
}

// ---------------- K3 GEMM: D[co][l] = sum_ci,tap W[co][ci] * S[l+shift][ci] --
// w_frag (A): lane m=li16 -> co, k = quad*8+e  -> coalesced 1KB global chunk
// x_frag (B): lane n=li16 -> l,  k = quad*8+e  -> ds_read_b128 of S row
// C/D: lane (li16) = l within 16-block j; regs = co (quad*4 + r, tile i)
// Each wave: co in [w*32, w*32+32), all 128 l  -> acc[2][8]
template <int TAPS, int DIL>
__device__ __forceinline__ void run_gemm(f32x4 (*acc)[8],
                                         const u16* __restrict__ Wg,
                                         const u16* __restrict__ S, int li16,
                                         int quad, int w) {
  const u16* wbase = Wg + w * 1024 + li16 * 32 + quad * 8;
  for (int kc = 0; kc < 4; ++kc) {
#pragma unroll
    for (int tap = 0; tap < TAPS; ++tap) {
      const int shift = (TAPS == 3) ? (tap - 1) * DIL : 0;
      const u16* wp = wbase + (kc * TAPS + tap) * 4096;
      short8 a0 = *(const short8*)wp;
      short8 a1 = *(const short8*)(wp + 512);
      int base_row = 4 + li16 + shift;
      int m0 = mod17(kc * 4 + quad + base_row);
      short8 b[8];
#pragma unroll
      for (int j = 0; j < 8; ++j) {
        int mj = m0 - j;
        mj += (mj < 0) ? 17 : 0;
        b[j] = *(const short8*)&S[(base_row + 16 * j) * 136 + mj * 8];
      }
#pragma unroll
      for (int j = 0; j < 8; ++j) {
        acc[0][j] = __builtin_amdgcn_mfma_f32_16x16x32_bf16(a0, b[j], acc[0][j], 0, 0, 0);
        acc[1][j] = __builtin_amdgcn_mfma_f32_16x16x32_bf16(a1, b[j], acc[1][j], 0, 0, 0);
      }
    }
  }
}

__device__ __forceinline__ void zero_acc(f32x4 (*acc)[8]) {
#pragma unroll
  for (int i = 0; i < 2; ++i)
#pragma unroll
    for (int j = 0; j < 8; ++j) acc[i][j] = (f32x4){0.f, 0.f, 0.f, 0.f};
}

// conv stage: gemm -> +bias -> GELU -> LN over l (in-wave stats) -> S
template <int DIL>
__device__ __forceinline__ void conv_stage(
    f32x4 (*acc)[8], const u16* __restrict__ Wg, u16* S, float* scr, int t,
    int li16, int quad, int w, const float* __restrict__ cb,
    const float* __restrict__ gw, const float* __restrict__ gb) {
  __syncthreads();  // prev S writes + prev scr reads done
  if (t < 128) {
    scr[CVEC + t] = cb[t];
    scr[GV + t] = gw[t];
    scr[BV + t] = gb[t];
  }
  zero_acc(acc);
  run_gemm<3, DIL>(acc, Wg, S, li16, quad, w);
  __syncthreads();  // S reads done; scr fills visible
  int cobase = w * 32;
#pragma unroll
  for (int i = 0; i < 2; ++i) {
    f32x4 b4 = *(const f32x4*)&scr[CVEC + cobase + i * 16 + quad * 4];
    f32x4 s = (f32x4){0.f, 0.f, 0.f, 0.f}, ss = s;
#pragma unroll
    for (int j = 0; j < 8; ++j) {
#pragma unroll
      for (int r = 0; r < 4; ++r) acc[i][j][r] = gelu_exact(acc[i][j][r] + b4[r]);
      s += acc[i][j];
      ss += acc[i][j] * acc[i][j];
    }
    // reduce over the 16 l-lanes (within quad)
#pragma unroll
    for (int r = 0; r < 4; ++r) {
      float sv = s[r], sq = ss[r];
      sv += __shfl_xor(sv, 1, 64); sq += __shfl_xor(sq, 1, 64);
      sv += __shfl_xor(sv, 2, 64); sq += __shfl_xor(sq, 2, 64);
      sv += __shfl_xor(sv, 4, 64); sq += __shfl_xor(sq, 4, 64);
      sv += __shfl_xor(sv, 8, 64); sq += __shfl_xor(sq, 8, 64);
      s[r] = sv;
      ss[r] = sq;
    }
    f32x4 m, inv;
#pragma unroll
    for (int r = 0; r < 4; ++r) {
      m[r] = s[r] * (1.0f / 128.0f);
      float var = ss[r] * (1.0f / 128.0f) - m[r] * m[r];
      inv[r] = rsqrtf(var + EPS);
    }
    int c8 = w * 4 + 2 * i + (quad >> 1);
#pragma unroll
    for (int j = 0; j < 8; ++j) {
      int l = 16 * j + li16;
      int row = 4 + l;
      float gl = scr[GV + l], bl = scr[BV + l];
      int phys = mod17(c8 + row);
      float y0 = (acc[i][j][0] - m[0]) * inv[0] * gl + bl;
      float y1 = (acc[i][j][1] - m[1]) * inv[1] * gl + bl;
      float y2 = (acc[i][j][2] - m[2]) * inv[2] * gl + bl;
      float y3 = (acc[i][j][3] - m[3]) * inv[3] * gl + bl;
      uint2 pk;
      pk.x = pack2(y0, y1);
      pk.y = pack2(y2, y3);
      *(uint2*)&S[row * 136 + phys * 8 + (quad & 1) * 4] = pk;
    }
  }
}

__global__ __launch_bounds__(256, 3) void k_main(
    const int* __restrict__ nidx, const int* __restrict__ nlen,
    const u16* __restrict__ Hg, const u16* __restrict__ ssmW3,
    const float* __restrict__ ssm_b, const u16* __restrict__ convW3,
    const float* __restrict__ conv_b, const float* __restrict__ lnw,
    const float* __restrict__ lnb, const u16* __restrict__ outW3,
    const float* __restrict__ out_b, const float* __restrict__ W1,
    const float* __restrict__ b1, const float* __restrict__ W2,
    const float* __restrict__ b2, float* __restrict__ out) {
  __shared__ __align__(16) u16 S[136 * 136];
  __shared__ __align__(16) float scr[SCR_N];

  int n = blockIdx.x, t = threadIdx.x;
  int lane = t & 63, w = t >> 6;
  int li16 = lane & 15, quad = lane >> 4;
  int len = nlen[n];

  // zero guard rows (all 17 chunks; stay zero across all stages)
  if (t < 136) {
    int g = t / 17, c = t % 17;
    int row = (g < 4) ? g : 128 + g;
    uint4 z; z.x = 0; z.y = 0; z.z = 0; z.w = 0;
    *(uint4*)&S[row * 136 + c * 8] = z;
  }
  // gather: S row (4+l) = H[nidx[l]] masked, rotation-swizzled chunks
  {
    int l = t >> 1, h = t & 1;
    int nb = nidx[n * MAXL + l];
    bool valid = l < len;
    const uint4* Hrow = (const uint4*)(Hg + nb * HID + h * 64);
    int row = 4 + l;
#pragma unroll
    for (int mb = 0; mb < 8; ++mb) {
      uint4 v = Hrow[mb];
      if (!valid) { v.x = 0; v.y = 0; v.z = 0; v.w = 0; }
      int c8 = h * 8 + mb;
      int phys = mod17(c8 + row);
      *(uint4*)&S[row * 136 + phys * 8] = v;
    }
  }
  if (t < 128) scr[CVEC + t] = ssm_b[t];
  __syncthreads();

  f32x4 acc[2][8];

  // ---- S1: D = ssm_W^T · X  (+bias)
  zero_acc(acc);
  run_gemm<1, 0>(acc, ssmW3, S, li16, quad, w);
  __syncthreads();
  {
    int cobase = w * 32;
#pragma unroll
    for (int i = 0; i < 2; ++i) {
      f32x4 b4 = *(const f32x4*)&scr[CVEC + cobase + i * 16 + quad * 4];
      int c8 = w * 4 + 2 * i + (quad >> 1);
#pragma unroll
      for (int j = 0; j < 8; ++j) {
        int row = 4 + 16 * j + li16;
        int phys = mod17(c8 + row);
        uint2 pk;
        pk.x = pack2(acc[i][j][0] + b4[0], acc[i][j][1] + b4[1]);
        pk.y = pack2(acc[i][j][2] + b4[2], acc[i][j][3] + b4[3]);
        *(uint2*)&S[row * 136 + phys * 8 + (quad & 1) * 4] = pk;
      }
    }
  }

  // ---- 3 dilated conv layers (2 barriers each, in-wave LN stats)
  conv_stage<1>(acc, convW3, S, scr, t, li16, quad, w, conv_b, lnw, lnb);
  conv_stage<2>(acc, convW3 + 49152, S, scr, t, li16, quad, w, conv_b + HID,
                lnw + HID, lnb + HID);
  conv_stage<4>(acc, convW3 + 98304, S, scr, t, li16, quad, w,
                conv_b + 2 * HID, lnw + 2 * HID, lnb + 2 * HID);

  // ---- out projection + masked mean pool (in-wave reduction)
  __syncthreads();
  zero_acc(acc);
  run_gemm<1, 0>(acc, outW3, S, li16, quad, w);
  __syncthreads();
  {
    int cobase = w * 32;
    float denom = (len > 0) ? (float)len : 1.0f;
#pragma unroll
    for (int i = 0; i < 2; ++i) {
      f32x4 s = (f32x4){0.f, 0.f, 0.f, 0.f};
#pragma unroll
      for (int j = 0; j < 8; ++j) {
        int l = 16 * j + li16;
        if (l < len) s += acc[i][j];
      }
#pragma unroll
      for (int r = 0; r < 4; ++r) {
        float sv = s[r];
        sv += __shfl_xor(sv, 1, 64);
        sv += __shfl_xor(sv, 2, 64);
        sv += __shfl_xor(sv, 4, 64);
        sv += __shfl_xor(sv, 8, 64);
        s[r] = sv;
      }
      if (li16 == 0) {
        int co0 = cobase + 16 * i + quad * 4;
        f32x4 ob = *(const f32x4*)(out_b + co0);
        f32x4 pooled;
#pragma unroll
        for (int r = 0; r < 4; ++r)
          pooled[r] = (len > 0) ? (s[r] / denom + ob[r]) : 0.f;
        *(f32x4*)&scr[CVEC + co0] = pooled;
      }
    }
  }
  __syncthreads();
  // ---- classifier (parallel over 4 partials)
  {
    int part = t >> 6, j = t & 63;
    float s = 0.f;
    int c0 = part * 32;
#pragma unroll 8
    for (int c = c0; c < c0 + 32; ++c) s += scr[CVEC + c] * W1[c * 64 + j];
    scr[RS0 + j * 4 + part] = s;
  }
  __syncthreads();
  if (t < 64) {
    float z = b1[t] + scr[RS0 + t * 4] + scr[RS0 + t * 4 + 1] +
              scr[RS0 + t * 4 + 2] + scr[RS0 + t * 4 + 3];
    scr[GV + t] = gelu_exact(z);
  }
  __syncthreads();
  {
    int part = t >> 6, j = t & 63;
    float s = 0.f;
    int c0 = part * 16;
#pragma unroll 8
    for (int c = c0; c < c0 + 16; ++c) s += scr[GV + c] * W2[c * 64 + j];
    scr[RS0 + j * 4 + part] = s;
  }
  __syncthreads();
  if (t < 64) {
    out[n * NCLS + t] = b2[t] + scr[RS0 + t * 4] + scr[RS0 + t * 4 + 1] +
                        scr[RS0 + t * 4 + 2] + scr[RS0 + t * 4 + 3];
  }
}

extern "C" void kernel_launch(void* const* d_in, const int* in_sizes, int n_in,
                              void* d_out, int out_size, void* d_ws,
                              size_t ws_size, hipStream_t stream) {
  const float* node_feat = (const float*)d_in[0];
  const int* nidx = (const int*)d_in[1];
  const int* nlen = (const int*)d_in[2];
  const float* local_W = (const float*)d_in[3];
  const float* local_b = (const float*)d_in[4];
  const float* local_ln_w = (const float*)d_in[5];
  const float* local_ln_b = (const float*)d_in[6];
  const float* ssm_W = (const float*)d_in[7];
  const float* ssm_b = (const float*)d_in[8];
  const float* conv_w = (const float*)d_in[9];
  const float* conv_b = (const float*)d_in[10];
  const float* lnw = (const float*)d_in[11];
  const float* lnb = (const float*)d_in[12];
  const float* outW = (const float*)d_in[13];
  const float* outb = (const float*)d_in[14];
  const float* W1 = (const float*)d_in[15];
  const float* b1 = (const float*)d_in[16];
  const float* W2 = (const float*)d_in[17];
  const float* b2 = (const float*)d_in[18];

  u16* Hws = (u16*)d_ws;                // 16384*128 bf16
  u16* convW3 = Hws + NN * HID;         // 147456
  u16* ssmW3 = convW3 + CONV_ELEMS;     // 16384
  u16* outW3 = ssmW3 + HID * HID;       // 16384

  k_local_encoder<<<NN / 8, 128, 0, stream>>>(node_feat, local_W, local_b,
                                              local_ln_w, local_ln_b, Hws);
  k_prep<<<(PREP_TOTAL + 255) / 256, 256, 0, stream>>>(conv_w, ssm_W, outW,
                                                       convW3);
  k_main<<<NN, 256, 0, stream>>>(nidx, nlen, Hws, ssmW3, ssm_b, convW3, conv_b,
                                 lnw, lnb, outW3, outb, W1, b1, W2, b2,
                                 (float*)d_out);
}